// Round 9
// baseline (78.223 us; speedup 1.0000x reference)
//
#include <hip/hip_runtime.h>
#include <hip/hip_bf16.h>
#include <math.h>

// Problem constants
#define B_    16
#define C_    256
#define L_    64
#define N_    8192
#define HEAD_ 8
#define HC_   32        // C/HEAD
#define M_    12

#define SQRT32F 5.656854249492380f
#define PI_F    3.14159265358979323846f
#define BN_INV  0.99999500003749969f     // 1/sqrt(1+1e-5)

// ---------------------------------------------------------------------------
// Kernel 1: fused encoder+decoder per (b,h). 128 blocks x 512 threads.
// GEMM uses wave-per-row decomposition: weight rows are wave-uniform ->
// s_load (scalar pipe); X read once per kk as conflict-free ds_read_b32.
// ---------------------------------------------------------------------------
__global__ __launch_bounds__(512) void fused_enc(
    const float* __restrict__ xt, const float* __restrict__ enc_w,
    const float* __restrict__ enc_b, const float* __restrict__ weights,
    const float* __restrict__ dec_w, const float* __restrict__ dec_b,
    const float* __restrict__ mt, float* __restrict__ xnp_out)
{
    __shared__ float Xs[C_][L_];          // 64 KB   xt[b] as [c][l]
    __shared__ float qkv_s[96][68];       // 26.1 KB rows 0..31 q, 32..63 k, 64..95 v
    __shared__ float P[L_][68];           // 17 KB
    __shared__ float enc_t[HC_][68];      // 8.5 KB
    __shared__ float qvs[HC_];
    __shared__ float aw[L_];
    const int t = threadIdx.x;            // 0..511
    const int b = blockIdx.x >> 3;
    const int h = blockIdx.x & 7;
    const float* xtb = xt + (size_t)b * (C_ * L_);

    // ---- phase 1: stage xt[b] (coalesced b128) ----
    #pragma unroll
    for (int i = 0; i < 8; ++i) {
        int q = t + i * 512;              // 0..4095 quads
        int c = q >> 4, l4 = (q & 15) * 4;
        *reinterpret_cast<float4*>(&Xs[c][l4]) =
            *reinterpret_cast<const float4*>(&xtb[q * 4]);
    }
    __syncthreads();

    // ---- phase 2: qkv GEMM, wave-per-row. wave wid owns rows wid*12..+11 ----
    {
        const int wid  = __builtin_amdgcn_readfirstlane(t >> 6);  // 0..7
        const int lane = t & 63;                                  // output col l
        const float* wr[12];
        float bias[12];
        #pragma unroll
        for (int r = 0; r < 12; ++r) {
            int o_loc = wid * 12 + r;          // 0..95
            int sec = o_loc >> 5, cc = o_loc & 31;
            int og = sec * C_ + h * HC_ + cc;
            wr[r] = enc_w + (size_t)og * C_;   // wave-uniform -> s_load
            bias[r] = enc_b[og];
        }
        float acc[12] = {};
        for (int c0 = 0; c0 < C_; c0 += 4) {
            float x0 = Xs[c0 + 0][lane];
            float x1 = Xs[c0 + 1][lane];
            float x2 = Xs[c0 + 2][lane];
            float x3 = Xs[c0 + 3][lane];
            #pragma unroll
            for (int r = 0; r < 12; ++r) {
                acc[r] += wr[r][c0 + 0] * x0 + wr[r][c0 + 1] * x1
                        + wr[r][c0 + 2] * x2 + wr[r][c0 + 3] * x3;
            }
        }
        #pragma unroll
        for (int r = 0; r < 12; ++r)
            qkv_s[wid * 12 + r][lane] = acc[r] + bias[r];
    }
    // qv = dec_w[h-slice] @ mt + dec_b (128 threads, 4 partials/row)
    if (t < 128) {
        int cc = t >> 2, part = t & 3;
        const float* wrq = dec_w + (size_t)(h * HC_ + cc) * C_ + part * 64;
        const float* mp = mt + part * 64;
        float s = 0.f;
        #pragma unroll
        for (int j = 0; j < 16; ++j) {
            float4 w4 = *reinterpret_cast<const float4*>(&wrq[j * 4]);
            float4 m4 = *reinterpret_cast<const float4*>(&mp[j * 4]);
            s += w4.x * m4.x + w4.y * m4.y + w4.z * m4.z + w4.w * m4.w;
        }
        s += __shfl_xor(s, 1);
        s += __shfl_xor(s, 2);
        if (part == 0) qvs[cc] = s + dec_b[h * HC_ + cc];
    }
    __syncthreads();

    // ---- phase 3a: scores, 4x4 register blocking (256 threads) ----
    if (t < 256) {
        const int l0  = (t >> 4) * 4;     // query quad
        const int lp0 = (t & 15) * 4;     // key quad
        float sc[4][4] = {};
        #pragma unroll
        for (int cc = 0; cc < HC_; ++cc) {
            float4 q4 = *reinterpret_cast<const float4*>(&qkv_s[cc][l0]);
            float4 k4 = *reinterpret_cast<const float4*>(&qkv_s[32 + cc][lp0]);
            float qs[4] = {q4.x, q4.y, q4.z, q4.w};
            #pragma unroll
            for (int i = 0; i < 4; ++i) {
                sc[i][0] += qs[i] * k4.x; sc[i][1] += qs[i] * k4.y;
                sc[i][2] += qs[i] * k4.z; sc[i][3] += qs[i] * k4.w;
            }
        }
        #pragma unroll
        for (int i = 0; i < 4; ++i) {
            float4 v = make_float4(sc[i][0] * SQRT32F, sc[i][1] * SQRT32F,
                                   sc[i][2] * SQRT32F, sc[i][3] * SQRT32F);
            *reinterpret_cast<float4*>(&P[l0 + i][lp0]) = v;
        }
    }
    __syncthreads();

    // ---- phase 3b: softmax, 4 threads/row ----
    if (t < 256) {
        int l = t >> 2, p0 = (t & 3) * 16;
        float m = -1e30f;
        #pragma unroll
        for (int j = 0; j < 16; ++j) m = fmaxf(m, P[l][p0 + j]);
        m = fmaxf(m, __shfl_xor(m, 1));
        m = fmaxf(m, __shfl_xor(m, 2));
        float sum = 0.f;
        #pragma unroll
        for (int j = 0; j < 16; ++j) {
            float e = __expf(P[l][p0 + j] - m);
            P[l][p0 + j] = e;
            sum += e;
        }
        sum += __shfl_xor(sum, 1);
        sum += __shfl_xor(sum, 2);
        float inv = 1.0f / sum;
        #pragma unroll
        for (int j = 0; j < 16; ++j) P[l][p0 + j] *= inv;
    }
    __syncthreads();

    // ---- phase 3c: PV (4l x 2cc register block) + Fourier + residual ----
    if (t < 256) {
        const int l0 = (t >> 4) * 4;      // 16 l-quads
        const int c0 = (t & 15) * 2;      // 16 cc-pairs
        float a[4][2] = {};
        #pragma unroll
        for (int sq = 0; sq < 16; ++sq) {
            float4 p4[4], v4[2];
            #pragma unroll
            for (int i = 0; i < 4; ++i)
                p4[i] = *reinterpret_cast<const float4*>(&P[l0 + i][sq * 4]);
            #pragma unroll
            for (int j = 0; j < 2; ++j)
                v4[j] = *reinterpret_cast<const float4*>(&qkv_s[64 + c0 + j][sq * 4]);
            #pragma unroll
            for (int i = 0; i < 4; ++i)
                #pragma unroll
                for (int j = 0; j < 2; ++j)
                    a[i][j] += p4[i].x * v4[j].x + p4[i].y * v4[j].y
                             + p4[i].z * v4[j].z + p4[i].w * v4[j].w;
        }
        #pragma unroll
        for (int j = 0; j < 2; ++j) {
            int c = h * HC_ + c0 + j;
            const float* wrf = weights + c * (2 * M_);
            float vv[4];
            #pragma unroll
            for (int i = 0; i < 4; ++i) {
                float val = Xs[c][l0 + i];
                float base = a[i][j] * (PI_F / (float)M_);
                #pragma unroll
                for (int m = 0; m < M_; ++m) {
                    float sn, cs;
                    __sincosf((float)m * base, &sn, &cs);
                    val += wrf[m] * sn + wrf[M_ + m] * cs;
                }
                vv[i] = val;
            }
            *reinterpret_cast<float4*>(&enc_t[c0 + j][l0]) =
                make_float4(vv[0], vv[1], vv[2], vv[3]);
        }
    }
    __syncthreads();

    // ---- phase 4: decoder attention (constant query) ----
    if (t < L_) {
        float s = 0.f;
        #pragma unroll
        for (int cc = 0; cc < HC_; ++cc) s += qvs[cc] * enc_t[cc][t];
        s *= SQRT32F;
        float m = s;
        #pragma unroll
        for (int off = 32; off >= 1; off >>= 1) m = fmaxf(m, __shfl_xor(m, off));
        float e = __expf(s - m);
        float sum = e;
        #pragma unroll
        for (int off = 32; off >= 1; off >>= 1) sum += __shfl_xor(sum, off);
        aw[t] = e / sum;
    }
    __syncthreads();
    if (t < HC_) {
        float a = 0.f;
        #pragma unroll
        for (int k4 = 0; k4 < L_; k4 += 4) {
            float4 a4 = *reinterpret_cast<const float4*>(&aw[k4]);
            float4 v4 = *reinterpret_cast<const float4*>(&enc_t[t][k4]);
            a += a4.x * v4.x + a4.y * v4.y + a4.z * v4.z + a4.w * v4.w;
        }
        int c = h * HC_ + t;
        xnp_out[b * C_ + c] = a + mt[c];
    }
}

// ---------------------------------------------------------------------------
// Kernel 2: broadcast out0 + (fc1/fc2 + broadcast) out1.  (proven)
// ---------------------------------------------------------------------------
__global__ __launch_bounds__(256) void bcast_fc(const float* __restrict__ xnp,
                                                const float* __restrict__ fc1_w,
                                                const float* __restrict__ fc1_g,
                                                const float* __restrict__ fc1_b,
                                                const float* __restrict__ fc2_w,
                                                const float* __restrict__ fc2_g,
                                                const float* __restrict__ fc2_b,
                                                float* __restrict__ out) {
    const int t = threadIdx.x;
    const int blk = blockIdx.x;
    if (blk < 4096) {
        float v = xnp[blk];
        float4 V = make_float4(v, v, v, v);
        float4* row = reinterpret_cast<float4*>(out + (size_t)blk * N_);
        #pragma unroll
        for (int i = 0; i < 8; ++i) row[t + i * 256] = V;   // 2048 x 16B
    } else {
        int b = blk - 4096;
        __shared__ float xs[C_];
        __shared__ float y1[C_];
        __shared__ float y2s[4];
        xs[t] = xnp[b * C_ + t];
        __syncthreads();
        {
            const float* wrow = fc1_w + (size_t)t * C_;
            float s = 0.f;
            #pragma unroll 8
            for (int c4 = 0; c4 < C_; c4 += 4) {
                float4 w4 = *reinterpret_cast<const float4*>(&wrow[c4]);
                float4 x4 = *reinterpret_cast<const float4*>(&xs[c4]);
                s += w4.x * x4.x + w4.y * x4.y + w4.z * x4.z + w4.w * x4.w;
            }
            float y = fc1_g[t] * s * BN_INV + fc1_b[t];
            y1[t] = (y >= 0.f) ? y : 0.2f * y;
        }
        __syncthreads();
        if (t < 3) {
            const float* wrow = fc2_w + t * C_;
            float s = 0.f;
            #pragma unroll 8
            for (int c4 = 0; c4 < C_; c4 += 4) {
                float4 w4 = *reinterpret_cast<const float4*>(&wrow[c4]);
                float4 x4 = *reinterpret_cast<const float4*>(&y1[c4]);
                s += w4.x * x4.x + w4.y * x4.y + w4.z * x4.z + w4.w * x4.w;
            }
            float y = fc2_g[t] * s * BN_INV + fc2_b[t];
            y2s[t] = (y >= 0.f) ? y : 0.2f * y;
        }
        __syncthreads();
        float v0 = y2s[0], v1 = y2s[1], v2 = y2s[2];
        float4 pat[3] = { make_float4(v0, v1, v2, v0),
                          make_float4(v1, v2, v0, v1),
                          make_float4(v2, v0, v1, v2) };
        float4* o1 = reinterpret_cast<float4*>(
            out + (size_t)B_ * C_ * N_ + (size_t)b * (N_ * 3));
        #pragma unroll
        for (int i = 0; i < 24; ++i) {       // 6144 float4 = 8192*3 f32
            int f = t + i * 256;
            o1[f] = pat[f % 3];
        }
    }
}

// ---------------------------------------------------------------------------
extern "C" void kernel_launch(void* const* d_in, const int* in_sizes, int n_in,
                              void* d_out, int out_size, void* d_ws, size_t ws_size,
                              hipStream_t stream) {
    const float* xt      = (const float*)d_in[0];
    // d_in[1] = xn : unused (length N is compile-time)
    const float* weights = (const float*)d_in[2];
    const float* mt      = (const float*)d_in[3];
    const float* enc_w   = (const float*)d_in[4];
    const float* enc_b   = (const float*)d_in[5];
    const float* dec_w   = (const float*)d_in[6];
    const float* dec_b   = (const float*)d_in[7];
    const float* fc1_w   = (const float*)d_in[8];
    const float* fc1_g   = (const float*)d_in[9];
    const float* fc1_b   = (const float*)d_in[10];
    const float* fc2_w   = (const float*)d_in[11];
    const float* fc2_g   = (const float*)d_in[12];
    const float* fc2_b   = (const float*)d_in[13];

    float* ws  = (float*)d_ws;
    float* xnp = ws;                  // 4096 floats

    float* out = (float*)d_out;

    fused_enc<<<128, 512, 0, stream>>>(xt, enc_w, enc_b, weights,
                                       dec_w, dec_b, mt, xnp);
    bcast_fc<<<4112, 256, 0, stream>>>(xnp, fc1_w, fc1_g, fc1_b,
                                       fc2_w, fc2_g, fc2_b, out);
}

// Round 10
// 59.131 us; speedup vs baseline: 1.3229x; 1.3229x over previous
//
#include <hip/hip_runtime.h>
#include <hip/hip_bf16.h>
#include <math.h>

// Problem constants
#define B_    16
#define C_    256
#define L_    64
#define N_    8192
#define HEAD_ 8
#define HC_   32        // C/HEAD
#define M_    12

#define SQRT32F 5.656854249492380f
#define PI_F    3.14159265358979323846f
#define BN_INV  0.99999500003749969f     // 1/sqrt(1+1e-5)

typedef float v4f __attribute__((ext_vector_type(4)));

// ---------------------------------------------------------------------------
// Kernel 1: fused encoder+decoder per (b,h). 128 blocks x 512 threads.
// (verbatim round-8 structure — measured baseline)
// ---------------------------------------------------------------------------
__global__ __launch_bounds__(512) void fused_enc(
    const float* __restrict__ xt, const float* __restrict__ enc_w,
    const float* __restrict__ enc_b, const float* __restrict__ weights,
    const float* __restrict__ dec_w, const float* __restrict__ dec_b,
    const float* __restrict__ mt, float* __restrict__ xnp_out)
{
    __shared__ float Xs[C_][L_];          // 64 KB   xt[b] as [c][l]
    __shared__ float qkv_s[96][68];       // rows 0..31 q, 32..63 k, 64..95 v
    __shared__ float P[L_][68];
    __shared__ float enc_t[HC_][68];
    __shared__ float qvs[HC_];
    __shared__ float aw[L_];
    const int t = threadIdx.x;            // 0..511
    const int b = blockIdx.x >> 3;
    const int h = blockIdx.x & 7;
    const float* xtb = xt + (size_t)b * (C_ * L_);

    // ---- phase 1: stage xt[b] ----
    #pragma unroll
    for (int i = 0; i < 8; ++i) {
        int q = t + i * 512;
        int c = q >> 4, l4 = (q & 15) * 4;
        *reinterpret_cast<float4*>(&Xs[c][l4]) =
            *reinterpret_cast<const float4*>(&xtb[q * 4]);
    }
    __syncthreads();

    // ---- phase 2: qkv GEMM. thread (ty,tx): rows ty*3..+2, cols tx*4..+3 ----
    {
        const int tx = t & 15, ty = t >> 4;    // ty 0..31
        float acc[3][4] = {};
        int og[3];
        const float* wrow[3];
        #pragma unroll
        for (int r = 0; r < 3; ++r) {
            int o_loc = ty * 3 + r;            // 0..95
            int sec = o_loc >> 5, cc = o_loc & 31;
            og[r] = sec * C_ + h * HC_ + cc;
            wrow[r] = enc_w + (size_t)og[r] * C_;
        }
        #pragma unroll 2
        for (int c0 = 0; c0 < C_; c0 += 4) {
            float4 x0 = *reinterpret_cast<const float4*>(&Xs[c0 + 0][tx * 4]);
            float4 x1 = *reinterpret_cast<const float4*>(&Xs[c0 + 1][tx * 4]);
            float4 x2 = *reinterpret_cast<const float4*>(&Xs[c0 + 2][tx * 4]);
            float4 x3 = *reinterpret_cast<const float4*>(&Xs[c0 + 3][tx * 4]);
            #pragma unroll
            for (int r = 0; r < 3; ++r) {
                float4 w4 = *reinterpret_cast<const float4*>(&wrow[r][c0]);
                acc[r][0] += w4.x * x0.x + w4.y * x1.x + w4.z * x2.x + w4.w * x3.x;
                acc[r][1] += w4.x * x0.y + w4.y * x1.y + w4.z * x2.y + w4.w * x3.y;
                acc[r][2] += w4.x * x0.z + w4.y * x1.z + w4.z * x2.z + w4.w * x3.z;
                acc[r][3] += w4.x * x0.w + w4.y * x1.w + w4.z * x2.w + w4.w * x3.w;
            }
        }
        #pragma unroll
        for (int r = 0; r < 3; ++r) {
            float bias = enc_b[og[r]];
            float4 v = make_float4(acc[r][0] + bias, acc[r][1] + bias,
                                   acc[r][2] + bias, acc[r][3] + bias);
            *reinterpret_cast<float4*>(&qkv_s[ty * 3 + r][tx * 4]) = v;
        }
    }
    // qv: 32 rows x 4 partial-threads, shfl-xor combine
    if (t < 128) {
        int cc = t >> 2, part = t & 3;
        const float* wr = dec_w + (size_t)(h * HC_ + cc) * C_ + part * 64;
        const float* mp = mt + part * 64;
        float s = 0.f;
        #pragma unroll
        for (int j = 0; j < 16; ++j) {
            float4 w4 = *reinterpret_cast<const float4*>(&wr[j * 4]);
            float4 m4 = *reinterpret_cast<const float4*>(&mp[j * 4]);
            s += w4.x * m4.x + w4.y * m4.y + w4.z * m4.z + w4.w * m4.w;
        }
        s += __shfl_xor(s, 1);
        s += __shfl_xor(s, 2);
        if (part == 0) qvs[cc] = s + dec_b[h * HC_ + cc];
    }
    __syncthreads();

    // ---- phase 3a: scores ----
    #pragma unroll
    for (int i = 0; i < 2; ++i) {
        int q = t + i * 512;
        int l = q >> 4, lq = (q & 15) * 4;
        float4 a4 = make_float4(0.f, 0.f, 0.f, 0.f);
        #pragma unroll
        for (int cc = 0; cc < HC_; ++cc) {
            float qv_ = qkv_s[cc][l];
            float4 k4 = *reinterpret_cast<const float4*>(&qkv_s[32 + cc][lq]);
            a4.x += qv_ * k4.x; a4.y += qv_ * k4.y;
            a4.z += qv_ * k4.z; a4.w += qv_ * k4.w;
        }
        a4.x *= SQRT32F; a4.y *= SQRT32F; a4.z *= SQRT32F; a4.w *= SQRT32F;
        *reinterpret_cast<float4*>(&P[l][lq]) = a4;
    }
    __syncthreads();

    // ---- phase 3b: softmax, 4 threads/row ----
    if (t < 256) {
        int l = t >> 2, p0 = (t & 3) * 16;
        float m = -1e30f;
        #pragma unroll
        for (int j = 0; j < 16; ++j) m = fmaxf(m, P[l][p0 + j]);
        m = fmaxf(m, __shfl_xor(m, 1));
        m = fmaxf(m, __shfl_xor(m, 2));
        float sum = 0.f;
        #pragma unroll
        for (int j = 0; j < 16; ++j) {
            float e = __expf(P[l][p0 + j] - m);
            P[l][p0 + j] = e;
            sum += e;
        }
        sum += __shfl_xor(sum, 1);
        sum += __shfl_xor(sum, 2);
        float inv = 1.0f / sum;
        #pragma unroll
        for (int j = 0; j < 16; ++j) P[l][p0 + j] *= inv;
    }
    __syncthreads();

    // ---- phase 3c: PV + Fourier + residual -> enc_t ----
    #pragma unroll
    for (int i = 0; i < 4; ++i) {
        int e  = t + i * 512;
        int cc = e >> 6, l = e & 63;
        float a = 0.f;
        #pragma unroll
        for (int sq = 0; sq < 16; ++sq) {
            float4 p4 = *reinterpret_cast<const float4*>(&P[l][sq * 4]);
            float4 v4 = *reinterpret_cast<const float4*>(&qkv_s[64 + cc][sq * 4]);
            a += p4.x * v4.x + p4.y * v4.y + p4.z * v4.z + p4.w * v4.w;
        }
        int c = h * HC_ + cc;
        float val = Xs[c][l];
        const float* wr = weights + c * (2 * M_);
        float base = a * (PI_F / (float)M_);
        #pragma unroll
        for (int m = 0; m < M_; ++m) {
            float sn, cs;
            __sincosf((float)m * base, &sn, &cs);
            val += wr[m] * sn + wr[M_ + m] * cs;
        }
        enc_t[cc][l] = val;
    }
    __syncthreads();

    // ---- phase 4: decoder attention (constant query) ----
    if (t < L_) {
        float s = 0.f;
        #pragma unroll
        for (int cc = 0; cc < HC_; ++cc) s += qvs[cc] * enc_t[cc][t];
        s *= SQRT32F;
        float m = s;
        #pragma unroll
        for (int off = 32; off >= 1; off >>= 1) m = fmaxf(m, __shfl_xor(m, off));
        float e = __expf(s - m);
        float sum = e;
        #pragma unroll
        for (int off = 32; off >= 1; off >>= 1) sum += __shfl_xor(sum, off);
        aw[t] = e / sum;
    }
    __syncthreads();
    if (t < HC_) {
        float a = 0.f;
        #pragma unroll
        for (int k4 = 0; k4 < L_; k4 += 4) {
            float4 a4 = *reinterpret_cast<const float4*>(&aw[k4]);
            float4 v4 = *reinterpret_cast<const float4*>(&enc_t[t][k4]);
            a += a4.x * v4.x + a4.y * v4.y + a4.z * v4.z + a4.w * v4.w;
        }
        int c = h * HC_ + t;
        xnp_out[b * C_ + c] = a + mt[c];
    }
}

// ---------------------------------------------------------------------------
// Kernel 2 (rewritten): fc blocks FIRST (no straggler tail), nontemporal
// stores for all 134 MB of streaming output.
//   blocks 0..15:     fc1/fc2 for batch b=blk, then out1[b] (96 KB, nt)
//   blocks 16..4111:  out0 row (blk-16): 32 KB splat (nt)
// ---------------------------------------------------------------------------
__global__ __launch_bounds__(256) void bcast_fc(const float* __restrict__ xnp,
                                                const float* __restrict__ fc1_w,
                                                const float* __restrict__ fc1_g,
                                                const float* __restrict__ fc1_b,
                                                const float* __restrict__ fc2_w,
                                                const float* __restrict__ fc2_g,
                                                const float* __restrict__ fc2_b,
                                                float* __restrict__ out) {
    const int t = threadIdx.x;
    const int blk = blockIdx.x;
    if (blk >= 16) {
        int rowid = blk - 16;                 // (b,c) row
        float v = xnp[rowid];
        v4f V = {v, v, v, v};
        v4f* row = reinterpret_cast<v4f*>(out + (size_t)rowid * N_);
        #pragma unroll
        for (int i = 0; i < 8; ++i)
            __builtin_nontemporal_store(V, &row[t + i * 256]);   // 2048 x 16B
    } else {
        int b = blk;
        __shared__ float xs[C_];
        __shared__ float y1[C_];
        __shared__ float y2s[4];
        xs[t] = xnp[b * C_ + t];
        __syncthreads();
        // fc1 + BN + LeakyReLU
        {
            const float* wrow = fc1_w + (size_t)t * C_;
            float s = 0.f;
            #pragma unroll 8
            for (int c4 = 0; c4 < C_; c4 += 4) {
                float4 w4 = *reinterpret_cast<const float4*>(&wrow[c4]);
                float4 x4 = *reinterpret_cast<const float4*>(&xs[c4]);
                s += w4.x * x4.x + w4.y * x4.y + w4.z * x4.z + w4.w * x4.w;
            }
            float y = fc1_g[t] * s * BN_INV + fc1_b[t];
            y1[t] = (y >= 0.f) ? y : 0.2f * y;
        }
        __syncthreads();
        if (t < 3) {
            const float* wrow = fc2_w + t * C_;
            float s = 0.f;
            #pragma unroll 8
            for (int c4 = 0; c4 < C_; c4 += 4) {
                float4 w4 = *reinterpret_cast<const float4*>(&wrow[c4]);
                float4 x4 = *reinterpret_cast<const float4*>(&y1[c4]);
                s += w4.x * x4.x + w4.y * x4.y + w4.z * x4.z + w4.w * x4.w;
            }
            float y = fc2_g[t] * s * BN_INV + fc2_b[t];
            y2s[t] = (y >= 0.f) ? y : 0.2f * y;
        }
        __syncthreads();
        float v0 = y2s[0], v1 = y2s[1], v2 = y2s[2];
        v4f pat0 = {v0, v1, v2, v0};
        v4f pat1 = {v1, v2, v0, v1};
        v4f pat2 = {v2, v0, v1, v2};
        // f = t + i*256; since 256 % 3 == 1, f % 3 == (t + i) % 3.
        int r = t % 3;
        v4f a = (r == 0) ? pat0 : (r == 1) ? pat1 : pat2;
        v4f bb = (r == 0) ? pat1 : (r == 1) ? pat2 : pat0;
        v4f c = (r == 0) ? pat2 : (r == 1) ? pat0 : pat1;
        v4f* o1 = reinterpret_cast<v4f*>(
            out + (size_t)B_ * C_ * N_ + (size_t)b * (N_ * 3));
        #pragma unroll
        for (int i = 0; i < 24; i += 3) {    // 6144 float4 = 8192*3 f32
            __builtin_nontemporal_store(a,  &o1[t + (i + 0) * 256]);
            __builtin_nontemporal_store(bb, &o1[t + (i + 1) * 256]);
            __builtin_nontemporal_store(c,  &o1[t + (i + 2) * 256]);
        }
    }
}

// ---------------------------------------------------------------------------
extern "C" void kernel_launch(void* const* d_in, const int* in_sizes, int n_in,
                              void* d_out, int out_size, void* d_ws, size_t ws_size,
                              hipStream_t stream) {
    const float* xt      = (const float*)d_in[0];
    // d_in[1] = xn : unused (length N is compile-time)
    const float* weights = (const float*)d_in[2];
    const float* mt      = (const float*)d_in[3];
    const float* enc_w   = (const float*)d_in[4];
    const float* enc_b   = (const float*)d_in[5];
    const float* dec_w   = (const float*)d_in[6];
    const float* dec_b   = (const float*)d_in[7];
    const float* fc1_w   = (const float*)d_in[8];
    const float* fc1_g   = (const float*)d_in[9];
    const float* fc1_b   = (const float*)d_in[10];
    const float* fc2_w   = (const float*)d_in[11];
    const float* fc2_g   = (const float*)d_in[12];
    const float* fc2_b   = (const float*)d_in[13];

    float* ws  = (float*)d_ws;
    float* xnp = ws;                  // 4096 floats

    float* out = (float*)d_out;

    fused_enc<<<128, 512, 0, stream>>>(xt, enc_w, enc_b, weights,
                                       dec_w, dec_b, mt, xnp);
    bcast_fc<<<4112, 256, 0, stream>>>(xnp, fc1_w, fc1_g, fc1_b,
                                       fc2_w, fc2_g, fc2_b, out);
}